// Round 2
// baseline (163.228 us; speedup 1.0000x reference)
//
#include <hip/hip_runtime.h>
#include <hip/hip_bf16.h>
#include <cstdint>

// GAT 3-layer pipeline, MI355X. B=4, N=2048, Fin=128, nhid=64, H=8, emb=64, nclass=16.
// fp32 tensors; d_out = [image_feature (4*2048*64) | pre (4*16)] fp32.
// Round 17: resubmission of round 16 (container infra failure, no measurement).
// (a) attn_k: 64 rows/wave (4 MFMA row-groups, 256-row blocks, 1 blk/CU), B/F/H read
// directly from L1/L2 (WhB is 256KB/instance -> cache-resident; LDS staging + per-step
// __syncthreads removed; manual 2-deep register pipeline). LDS only for the 80KB
// half-combine. (b) layer-2 GEMM fused with epilogue: 8-wave blocks, K split 4-ways
// across waves, 32KB LDS reduce -> pC2 16MB round-trip and gemm_epi_k launch removed.
// (c) layer3b folded into layer3a via agent-scope atomic ticket. 9 -> 7 launches.

#define NN 2048

typedef float f32x4 __attribute__((ext_vector_type(4)));
typedef __bf16 bf16x8 __attribute__((ext_vector_type(8)));
typedef _Float16 f16;
typedef _Float16 f16x8 __attribute__((ext_vector_type(8)));

// ---------------- fused prep: adj->u8 kb-tiled plane, Ws/W1 -> bf16 hi/lo frags ----
// pm layout: [kb(64)][i(2048)][jb(32)] u8 (0xFF if edge) — 4 MB, tiles contiguous.
__global__ __launch_bounds__(256) void prep_k(
    const int* __restrict__ adj, unsigned char* __restrict__ pm,
    const float* __restrict__ Ws, __bf16* __restrict__ WsFh, __bf16* __restrict__ WsFl,
    const float* __restrict__ W1, __bf16* __restrict__ W1Fh, __bf16* __restrict__ W1Fl,
    unsigned int* __restrict__ ticket) {
  const int bx = blockIdx.x, t = threadIdx.x;
  if (bx == 0 && t == 0) *ticket = 0u;  // reset layer3 ticket every graph replay
  if (bx < 2048) {
    const int i = bx;
#pragma unroll
    for (int jt = 0; jt < 8; ++jt) {
      const int j = jt * 256 + t;
      pm[((long)(j >> 5) << 16) + i * 32 + (j & 31)] =
          adj[(long)i * NN + j] > 0 ? 0xFFu : 0u;
    }
  } else if (bx < 2304) {
    const int idx = (bx - 2048) * 256 + t;  // 8 inst x 8192
    const int inst = idx >> 13;
    const int rem = idx & 8191;
    const int k = rem >> 6, n = rem & 63;
    const float v = Ws[(long)inst * 8192 + rem];
    const __bf16 vh = (__bf16)v;
    const int pos = ((k >> 5) * 4 + (n >> 4)) * 512 + (((k >> 3) & 3) * 16 + (n & 15)) * 8 + (k & 7);
    WsFh[(long)inst * 8192 + pos] = vh;
    WsFl[(long)inst * 8192 + pos] = (__bf16)(v - (float)vh);
  } else {
    const int idx = (bx - 2304) * 256 + t;  // 512 x 64
    const int k = idx >> 6, n = idx & 63;
    const float v = W1[idx];
    const __bf16 vh = (__bf16)v;
    const int pos = ((k >> 5) * 4 + (n >> 4)) * 512 + (((k >> 3) & 3) * 16 + (n & 15)) * 8 + (k & 7);
    W1Fh[pos] = vh;
    W1Fl[pos] = (__bf16)(v - (float)vh);
  }
}

// ---------------- MFMA GEMM layer-1 (M rows, N=64). 128 thr, 32 rows/block. --------
struct GemmLd {
  float4 a0, a1;
  bf16x8 bh[4], bl[4];
};

__global__ __launch_bounds__(128) void gemm_mfma_k(
    const float* __restrict__ Aall, const __bf16* __restrict__ WFhi,
    const __bf16* __restrict__ WFlo, const float* __restrict__ avecAll,
    f16* __restrict__ WhBAll, float* __restrict__ Eo, float* __restrict__ Go,
    f16* __restrict__ Fo, f16* __restrict__ Ho,
    int K, long aStrideB) {
  const int p = blockIdx.y;
  const float* A = Aall + (long)(p & 3) * aStrideB;
  const long wfOff = (long)(p >> 2) * K * 64;
  const bf16x8* BhF = (const bf16x8*)(WFhi + wfOff);
  const bf16x8* BlF = (const bf16x8*)(WFlo + wfOff);

  const int t = threadIdx.x, lane = t & 63, wave = t >> 6;
  const int quad = lane >> 4, lm = lane & 15;
  const int i0w = blockIdx.x * 32 + wave * 16;
  const float* Arow = A + (long)(i0w + lm) * K;
  const int kBeg = 0, kEnd = K;

  f32x4 acc[4];
#pragma unroll
  for (int nt = 0; nt < 4; ++nt) acc[nt] = (f32x4){0.f, 0.f, 0.f, 0.f};

  auto LOAD = [&](GemmLd& L, int k0) {
    L.a0 = *(const float4*)(Arow + k0 + quad * 8);
    L.a1 = *(const float4*)(Arow + k0 + quad * 8 + 4);
    const int bbase = (k0 >> 5) * 256 + lane;
#pragma unroll
    for (int nt = 0; nt < 4; ++nt) {
      L.bh[nt] = BhF[bbase + nt * 64];
      L.bl[nt] = BlF[bbase + nt * 64];
    }
  };
  auto STEP = [&](const GemmLd& L) {
    const float av8[8] = {L.a0.x, L.a0.y, L.a0.z, L.a0.w, L.a1.x, L.a1.y, L.a1.z, L.a1.w};
    bf16x8 ah, al;
#pragma unroll
    for (int j = 0; j < 8; ++j) {
      const __bf16 h = (__bf16)av8[j];
      ah[j] = h;
      al[j] = (__bf16)(av8[j] - (float)h);
    }
#pragma unroll
    for (int nt = 0; nt < 4; ++nt) {
      acc[nt] = __builtin_amdgcn_mfma_f32_16x16x32_bf16(ah, L.bh[nt], acc[nt], 0, 0, 0);
      acc[nt] = __builtin_amdgcn_mfma_f32_16x16x32_bf16(al, L.bh[nt], acc[nt], 0, 0, 0);
      acc[nt] = __builtin_amdgcn_mfma_f32_16x16x32_bf16(ah, L.bl[nt], acc[nt], 0, 0, 0);
    }
  };

  GemmLd La, Lb;
  LOAD(La, kBeg);
  for (int k0 = kBeg; k0 < kEnd; k0 += 64) {
    LOAD(Lb, k0 + 32);
    STEP(La);
    LOAD(La, (k0 + 64 < kEnd) ? k0 + 64 : kBeg);
    STEP(Lb);
  }

  const float* av = avecAll + (long)(p >> 2) * 128;
  f16* WhB = WhBAll + (long)p * NN * 64;
  float* E = Eo + (long)p * NN;
  float* G = Go + (long)p * NN;
  f16* F = Fo + (long)p * NN;
  f16* Hh = Ho + (long)p * NN;

  float alo[4], ahi[4];
#pragma unroll
  for (int nt = 0; nt < 4; ++nt) {
    alo[nt] = av[nt * 16 + lm];
    ahi[nt] = av[64 + nt * 16 + lm];
  }
#pragma unroll
  for (int reg = 0; reg < 4; ++reg) {
    float es = 0.f, ed = 0.f;
#pragma unroll
    for (int nt = 0; nt < 4; ++nt) {
      es += acc[nt][reg] * alo[nt];
      ed += acc[nt][reg] * ahi[nt];
    }
#pragma unroll
    for (int m = 1; m < 16; m <<= 1) {
      es += __shfl_xor(es, m);
      ed += __shfl_xor(ed, m);
    }
    if (lm == 0) {
      const int r = i0w + quad * 4 + reg;
      E[r] = __expf(es);
      G[r] = __expf(0.2f * es);
      F[r] = (f16)__expf(ed);
      Hh[r] = (f16)__expf(0.2f * ed);
    }
  }

  const int r0 = i0w + quad * 4;
  const long base = ((long)(r0 >> 5) * 4) * 512 + (((r0 >> 3) & 3) * 16 + lm) * 8 + (r0 & 7);
#pragma unroll
  for (int nt = 0; nt < 4; ++nt) {
    union { f16 h[4]; uint2 u; } pk;
#pragma unroll
    for (int q = 0; q < 4; ++q) pk.h[q] = (f16)acc[nt][q];
    *(uint2*)(WhB + base + nt * 512) = pk.u;
  }
}

// ---------------- layer-2 GEMM fused with epilogue (8 waves: 4 K-slices x 2 row-halves)
__global__ __launch_bounds__(512) void gemm2_k(
    const float* __restrict__ Aall, const __bf16* __restrict__ WFhi,
    const __bf16* __restrict__ WFlo, const float* __restrict__ avec,
    f16* __restrict__ WhBAll, float* __restrict__ Eo, float* __restrict__ Go,
    f16* __restrict__ Fo, f16* __restrict__ Ho) {
  const int p = blockIdx.y;
  const float* A = Aall + (long)p * NN * 512;
  const bf16x8* BhF = (const bf16x8*)WFhi;
  const bf16x8* BlF = (const bf16x8*)WFlo;
  const int t = threadIdx.x, lane = t & 63, wave = t >> 6;
  const int ks = wave & 3, rh = wave >> 2;
  const int quad = lane >> 4, lm = lane & 15;
  const int i0 = blockIdx.x * 32;
  const float* Arow = A + (long)(i0 + rh * 16 + lm) * 512;
  const int kBeg = ks * 128, kEnd = kBeg + 128;

  f32x4 acc[4];
#pragma unroll
  for (int nt = 0; nt < 4; ++nt) acc[nt] = (f32x4){0.f, 0.f, 0.f, 0.f};

  auto LOAD = [&](GemmLd& L, int k0) {
    L.a0 = *(const float4*)(Arow + k0 + quad * 8);
    L.a1 = *(const float4*)(Arow + k0 + quad * 8 + 4);
    const int bbase = (k0 >> 5) * 256 + lane;
#pragma unroll
    for (int nt = 0; nt < 4; ++nt) {
      L.bh[nt] = BhF[bbase + nt * 64];
      L.bl[nt] = BlF[bbase + nt * 64];
    }
  };
  auto STEP = [&](const GemmLd& L) {
    const float av8[8] = {L.a0.x, L.a0.y, L.a0.z, L.a0.w, L.a1.x, L.a1.y, L.a1.z, L.a1.w};
    bf16x8 ah, al;
#pragma unroll
    for (int j = 0; j < 8; ++j) {
      const __bf16 h = (__bf16)av8[j];
      ah[j] = h;
      al[j] = (__bf16)(av8[j] - (float)h);
    }
#pragma unroll
    for (int nt = 0; nt < 4; ++nt) {
      acc[nt] = __builtin_amdgcn_mfma_f32_16x16x32_bf16(ah, L.bh[nt], acc[nt], 0, 0, 0);
      acc[nt] = __builtin_amdgcn_mfma_f32_16x16x32_bf16(al, L.bh[nt], acc[nt], 0, 0, 0);
      acc[nt] = __builtin_amdgcn_mfma_f32_16x16x32_bf16(ah, L.bl[nt], acc[nt], 0, 0, 0);
    }
  };

  GemmLd La, Lb;
  LOAD(La, kBeg);
  for (int k0 = kBeg; k0 < kEnd; k0 += 64) {
    LOAD(Lb, k0 + 32);
    STEP(La);
    LOAD(La, (k0 + 64 < kEnd) ? k0 + 64 : kBeg);
    STEP(Lb);
  }

  // cross-wave K reduction: red[wave][nt][lane][reg]
  __shared__ __align__(16) float red[8][4][64][4];
#pragma unroll
  for (int nt = 0; nt < 4; ++nt) *(f32x4*)&red[wave][nt][lane][0] = acc[nt];
  __syncthreads();

  // epilogue: thread (rgrp=wave, n=lane) owns col n of rows rgrp*4..+3
  const int n = lane, rgrp = wave;
  const int rh2 = rgrp >> 2, q2 = rgrp & 3;
  const int ln = q2 * 16 + (n & 15), ntq = n >> 4;
  f32x4 c4 = *(const f32x4*)&red[rh2 * 4 + 0][ntq][ln][0];
#pragma unroll
  for (int ksum = 1; ksum < 4; ++ksum)
    c4 += *(const f32x4*)&red[rh2 * 4 + ksum][ntq][ln][0];

  f32x4 es4 = c4 * avec[n];
  f32x4 ed4 = c4 * avec[64 + n];
#pragma unroll
  for (int m = 1; m < 64; m <<= 1) {
#pragma unroll
    for (int q = 0; q < 4; ++q) {
      es4[q] += __shfl_xor(es4[q], m);
      ed4[q] += __shfl_xor(ed4[q], m);
    }
  }
  const int row0 = i0 + rgrp * 4;
  if (n == 0) {
#pragma unroll
    for (int reg = 0; reg < 4; ++reg) {
      const int row = row0 + reg;
      Eo[(long)p * NN + row] = __expf(es4[reg]);
      Go[(long)p * NN + row] = __expf(0.2f * es4[reg]);
      Fo[(long)p * NN + row] = (f16)__expf(ed4[reg]);
      Ho[(long)p * NN + row] = (f16)__expf(0.2f * ed4[reg]);
    }
  }
  f16* WhB = WhBAll + (long)p * NN * 64;
  union { f16 h[4]; uint2 u; } pk;
#pragma unroll
  for (int reg = 0; reg < 4; ++reg) pk.h[reg] = (f16)c4[reg];
  const long pos = ((long)(row0 >> 5) * 4 + ntq) * 512 +
                   ((((row0 >> 3) & 3) * 16 + (n & 15)) * 8) + (row0 & 7);
  *(uint2*)(WhB + pos) = pk.u;
}

// ---------------- attention: barrier-free, B/F/H direct from L1/L2, 64 rows/wave ----
// 512 thr = 8 waves: rw = wave&3 (64 rows each, block = 256 rows), half = wave>>2
// (kb-half). WhB is 256KB/instance -> cache-resident; no LDS staging, no per-step
// barriers. Manual 2-deep register pipeline hides L1/L2 latency. LDS only for the
// final half-combine.
struct KbLd {
  f16x8 F8, H8;
  f16x8 b[4];
  uint2 m[4];
};

__global__ __launch_bounds__(512) void attn_k(
    const f16* __restrict__ WhBAll, const float* __restrict__ Eb,
    const float* __restrict__ Gb, const f16* __restrict__ Fb,
    const f16* __restrict__ Hb, const unsigned char* __restrict__ pm,
    float* __restrict__ out1, int rowStride, long strideB,
    int jsCount, float* __restrict__ partAcc, float* __restrict__ partSum) {
  const int p = blockIdx.z;
  const int js = blockIdx.y;
  const f16* WhB = WhBAll + (long)p * NN * 64;
  const float* E = Eb + (long)p * NN;
  const float* G = Gb + (long)p * NN;
  const f16* Fg = Fb + (long)p * NN;
  const f16* Hg = Hb + (long)p * NN;
  const int t = threadIdx.x, lane = t & 63, wave = t >> 6;
  const int rw = wave & 3, half = wave >> 2;
  const int quad = lane >> 4, lm = lane & 15;
  const int i0 = blockIdx.x * 256;
  const int rbase = rw * 64;
  const int span = 64 / jsCount;      // kb per js job
  const int nIter = span / 2;         // kb per half (even, >=8)
  const int kbBeg = js * span + half * nIter, kbEnd = kbBeg + nIter;

  __shared__ __align__(16) float cmb[20480];  // 80 KB half-combine buffer

  f16x8 ev[4], gv[4];
#pragma unroll
  for (int g = 0; g < 4; ++g) {
    const int r = i0 + rbase + g * 16 + lm;
    const f16 e = (f16)E[r], gg = (f16)G[r];
#pragma unroll
    for (int j = 0; j < 8; ++j) { ev[g][j] = e; gv[g][j] = gg; }
  }

  f16x8 ones;
#pragma unroll
  for (int j = 0; j < 8; ++j) ones[j] = (lm == 0) ? (f16)1.0f : (f16)0.0f;

  f32x4 acc[4][4], sum[4];
#pragma unroll
  for (int g = 0; g < 4; ++g) {
    sum[g] = (f32x4){0.f, 0.f, 0.f, 0.f};
#pragma unroll
    for (int nt = 0; nt < 4; ++nt) acc[g][nt] = (f32x4){0.f, 0.f, 0.f, 0.f};
  }

  const unsigned char* mp[4];
#pragma unroll
  for (int g = 0; g < 4; ++g)
    mp[g] = pm + (long)(i0 + rbase + g * 16 + lm) * 32 + quad * 8;

  auto LD = [&](KbLd& L, int kb) {
    L.F8 = *(const f16x8*)(Fg + kb * 32 + quad * 8);
    L.H8 = *(const f16x8*)(Hg + kb * 32 + quad * 8);
#pragma unroll
    for (int nt = 0; nt < 4; ++nt)
      L.b[nt] = *(const f16x8*)(WhB + (long)kb * 2048 + (nt * 64 + lane) * 8);
#pragma unroll
    for (int g = 0; g < 4; ++g)
      L.m[g] = *(const uint2*)(mp[g] + ((long)kb << 16));
  };
  auto CP = [&](const KbLd& L) {
    union { f16x8 v; uint4 u4; } A[4];
#pragma unroll
    for (int g = 0; g < 4; ++g) {
      A[g].v = __builtin_elementwise_max(ev[g] * L.F8, gv[g] * L.H8);
      A[g].u4.x &= __builtin_amdgcn_perm(0u, L.m[g].x, 0x01010000u);
      A[g].u4.y &= __builtin_amdgcn_perm(0u, L.m[g].x, 0x03030202u);
      A[g].u4.z &= __builtin_amdgcn_perm(0u, L.m[g].y, 0x01010000u);
      A[g].u4.w &= __builtin_amdgcn_perm(0u, L.m[g].y, 0x03030202u);
    }
#pragma unroll
    for (int nt = 0; nt < 4; ++nt) {
#pragma unroll
      for (int g = 0; g < 4; ++g)
        acc[g][nt] = __builtin_amdgcn_mfma_f32_16x16x32_f16(A[g].v, L.b[nt], acc[g][nt], 0, 0, 0);
    }
#pragma unroll
    for (int g = 0; g < 4; ++g)
      sum[g] = __builtin_amdgcn_mfma_f32_16x16x32_f16(A[g].v, ones, sum[g], 0, 0, 0);
  };

  KbLd La, Lb2;
  LD(La, kbBeg);
  for (int kb = kbBeg; kb < kbEnd; kb += 2) {
    LD(Lb2, kb + 1);
    CP(La);
    if (kb + 2 < kbEnd) LD(La, kb + 2);
    CP(Lb2);
  }

  // ---- combine the two kb-halves via LDS (chunk-major, lane-contiguous 16B) ----
  if (half == 1) {
#pragma unroll
    for (int g = 0; g < 4; ++g) {
#pragma unroll
      for (int nt = 0; nt < 4; ++nt)
        *(f32x4*)&cmb[((rw * 20 + g * 4 + nt) * 64 + lane) * 4] = acc[g][nt];
      *(f32x4*)&cmb[((rw * 20 + 16 + g) * 64 + lane) * 4] = sum[g];
    }
  }
  __syncthreads();
  if (half == 1) return;
#pragma unroll
  for (int g = 0; g < 4; ++g) {
#pragma unroll
    for (int nt = 0; nt < 4; ++nt)
      acc[g][nt] += *(const f32x4*)&cmb[((rw * 20 + g * 4 + nt) * 64 + lane) * 4];
    sum[g] += *(const f32x4*)&cmb[((rw * 20 + 16 + g) * 64 + lane) * 4];
  }

  if (jsCount == 1) {
#pragma unroll
    for (int g = 0; g < 4; ++g) {
#pragma unroll
      for (int reg = 0; reg < 4; ++reg) {
        const int row = i0 + rbase + g * 16 + quad * 4 + reg;
        const float ls = __shfl(sum[g][reg], quad * 16);
        const float il = ls > 0.f ? 1.f / ls : 0.f;
#pragma unroll
        for (int nt = 0; nt < 4; ++nt) {
          float v = acc[g][nt][reg] * il;
          v = v > 0.f ? v : expm1f(v);  // elu
          const long o = (long)(p & 3) * strideB + (long)row * rowStride + (p >> 2) * 64 + nt * 16 + lm;
          out1[o] = v;
        }
      }
    }
  } else {
    float* pAcc = partAcc + ((long)p * jsCount + js) * NN * 64;
    float* pSum = partSum + ((long)p * jsCount + js) * NN;
#pragma unroll
    for (int g = 0; g < 4; ++g) {
#pragma unroll
      for (int reg = 0; reg < 4; ++reg) {
        const int row = i0 + rbase + g * 16 + quad * 4 + reg;
#pragma unroll
        for (int nt = 0; nt < 4; ++nt) pAcc[(long)row * 64 + nt * 16 + lm] = acc[g][nt][reg];
        if (lm == 0) pSum[row] = sum[g][reg];
      }
    }
  }
}

// ---------------- combine j-split partials: normalize + elu + dual write (512 blocks) ----
__global__ __launch_bounds__(256) void combine_k(const float* __restrict__ partAcc,
                                                 const float* __restrict__ partSum,
                                                 float* __restrict__ img,
                                                 float* __restrict__ out, int JS) {
  const long idx = (long)blockIdx.x * 256 + threadIdx.x;
  const int cg = idx & 15;
  const int row = (int)((idx >> 4) & (NN - 1));
  const int inst = (int)(idx >> 15);
  f32x4 v = (f32x4){0.f, 0.f, 0.f, 0.f};
  float s = 0.f;
  for (int js = 0; js < JS; ++js) {
    const long b = ((long)inst * JS + js) * NN;
    v += *(const f32x4*)(partAcc + (b + row) * 64 + cg * 4);
    s += partSum[b + row];
  }
  const float il = s > 0.f ? 1.f / s : 0.f;
  f32x4 r;
#pragma unroll
  for (int q = 0; q < 4; ++q) {
    float x = v[q] * il;
    r[q] = x > 0.f ? x : expm1f(x);
  }
  const long o = ((long)inst * NN + row) * 64 + cg * 4;
  *(f32x4*)(img + o) = r;
  *(f32x4*)(out + o) = r;
}

// ---------------- layer-3: on-the-fly Wh3, j-split partials; last block reduces ----
__global__ __launch_bounds__(256) void layer3a_k(
    const float* __restrict__ img, const float* __restrict__ W2,
    const float* __restrict__ a2, const unsigned char* __restrict__ pm,
    float* __restrict__ pOut /* [B][8][17] */, float* __restrict__ outPre,
    unsigned int* __restrict__ ticket) {
  const int bb = blockIdx.x, chunk = blockIdx.y, t = threadIdx.x;
  const float* A = img + (long)bb * NN * 64;
  __shared__ float w2alo[64], w2ahi[64];
  __shared__ float W2s[64][17];
  __shared__ float redc[4][17];
  __shared__ int lastS;
  if (t < 64) {
    float sl = 0.f, sh = 0.f;
#pragma unroll
    for (int c = 0; c < 16; ++c) {
      const float wv = W2[t * 16 + c];
      W2s[t][c] = wv;
      sl += wv * a2[c];
      sh += wv * a2[16 + c];
    }
    w2alo[t] = sl;
    w2ahi[t] = sh;
  }
  __syncthreads();

  float es = 0.f;
#pragma unroll 16
  for (int k = 0; k < 64; ++k) es += A[k] * w2alo[k];

  const int j = chunk * 256 + t;
  float arow[64];
#pragma unroll
  for (int q = 0; q < 16; ++q) *(f32x4*)(arow + q * 4) = *(const f32x4*)(A + (long)j * 64 + q * 4);
  float ed = 0.f;
#pragma unroll
  for (int k = 0; k < 64; ++k) ed += arow[k] * w2ahi[k];
  float e = es + ed;
  e = fmaxf(e, 0.2f * e);
  const float pv = pm[((long)(j >> 5) << 16) + (j & 31)] ? __expf(e) : 0.f;  // row 0 mask

  float acc[16];
#pragma unroll
  for (int c = 0; c < 16; ++c) {
    float wh = 0.f;
#pragma unroll
    for (int k = 0; k < 64; ++k) wh += arow[k] * W2s[k][c];
    acc[c] = pv * wh;
  }
  float lsum = pv;

#pragma unroll
  for (int off = 32; off > 0; off >>= 1) {
    lsum += __shfl_down(lsum, off);
#pragma unroll
    for (int c = 0; c < 16; ++c) acc[c] += __shfl_down(acc[c], off);
  }
  if ((t & 63) == 0) {
    const int wv = t >> 6;
#pragma unroll
    for (int c = 0; c < 16; ++c) redc[wv][c] = acc[c];
    redc[wv][16] = lsum;
  }
  __syncthreads();
  if (t < 17) {
    __hip_atomic_store(&pOut[((long)bb * 8 + chunk) * 17 + t],
                       redc[0][t] + redc[1][t] + redc[2][t] + redc[3][t],
                       __ATOMIC_RELAXED, __HIP_MEMORY_SCOPE_AGENT);
  }
  __syncthreads();
  if (t == 0)
    lastS = (__hip_atomic_fetch_add(ticket, 1u, __ATOMIC_ACQ_REL,
                                    __HIP_MEMORY_SCOPE_AGENT) == 31u);
  __syncthreads();
  if (lastS && t < 64) {
    const int b2 = t >> 4, c2 = t & 15;
    float a = 0.f, l = 0.f;
#pragma unroll
    for (int ch = 0; ch < 8; ++ch) {
      a += __hip_atomic_load(&pOut[((long)b2 * 8 + ch) * 17 + c2],
                             __ATOMIC_RELAXED, __HIP_MEMORY_SCOPE_AGENT);
      l += __hip_atomic_load(&pOut[((long)b2 * 8 + ch) * 17 + 16],
                             __ATOMIC_RELAXED, __HIP_MEMORY_SCOPE_AGENT);
    }
    float v = a / l;
    v = v > 0.f ? v : expm1f(v);
    outPre[b2 * 16 + c2] = v;
  }
}

// ---------------- host ----------------
extern "C" void kernel_launch(void* const* d_in, const int* in_sizes, int n_in,
                              void* d_out, int out_size, void* d_ws, size_t ws_size,
                              hipStream_t stream) {
  (void)in_sizes; (void)n_in; (void)out_size; (void)ws_size;
  constexpr int B = 4, N = NN, JS2 = 4;

  const float* slices = (const float*)d_in[0];
  const int* adj = (const int*)d_in[1];
  const float* Ws = (const float*)d_in[2];
  const float* As = (const float*)d_in[3];
  const float* W1 = (const float*)d_in[4];
  const float* a1 = (const float*)d_in[5];
  const float* W2 = (const float*)d_in[6];
  const float* a2 = (const float*)d_in[7];
  float* out = (float*)d_out;

  char* w = (char*)d_ws;
  size_t off = 0;
  auto alloc = [&](size_t bytes) {
    void* ptr = w + off;
    off += (bytes + 255) & ~(size_t)255;
    return ptr;
  };
  unsigned char* pm = (unsigned char*)alloc((size_t)64 * 65536);  // 4 MB kb-tiled mask
  __bf16* WsFh = (__bf16*)alloc((size_t)8 * 128 * 64 * 2);
  __bf16* WsFl = (__bf16*)alloc((size_t)8 * 128 * 64 * 2);
  __bf16* W1Fh = (__bf16*)alloc((size_t)512 * 64 * 2);
  __bf16* W1Fl = (__bf16*)alloc((size_t)512 * 64 * 2);
  f16* WhB1 = (f16*)alloc((size_t)32 * N * 64 * 2);  // 8 MB
  float* E1 = (float*)alloc((size_t)32 * N * 4);
  float* G1 = (float*)alloc((size_t)32 * N * 4);
  f16* F1 = (f16*)alloc((size_t)32 * N * 2);
  f16* H1 = (f16*)alloc((size_t)32 * N * 2);
  float* x = (float*)alloc((size_t)B * N * 512 * 4);  // 16 MB
  f16* WhB2 = (f16*)alloc((size_t)B * N * 64 * 2);
  float* E2 = (float*)alloc((size_t)B * N * 4);
  float* G2 = (float*)alloc((size_t)B * N * 4);
  f16* F2 = (f16*)alloc((size_t)B * N * 2);
  f16* H2 = (f16*)alloc((size_t)B * N * 2);
  float* img = (float*)alloc((size_t)B * N * 64 * 4);  // 2 MB
  float* pAcc2 = (float*)alloc((size_t)B * JS2 * N * 64 * 4);  // 8 MB
  float* pSum2 = (float*)alloc((size_t)B * JS2 * N * 4);
  float* pL3 = (float*)alloc((size_t)B * 8 * 17 * 4);
  unsigned int* ticket = (unsigned int*)alloc(256);

  prep_k<<<dim3(2432), dim3(256), 0, stream>>>(adj, pm, Ws, WsFh, WsFl, W1, W1Fh, W1Fl, ticket);

  // layer 1
  gemm_mfma_k<<<dim3(N / 32, 32), dim3(128), 0, stream>>>(
      slices, WsFh, WsFl, As, WhB1, E1, G1, F1, H1, 128, (long)N * 128);
  attn_k<<<dim3(N / 256, 1, 32), dim3(512), 0, stream>>>(
      WhB1, E1, G1, F1, H1, pm, x, 512, (long)N * 512,
      1, (float*)nullptr, (float*)nullptr);

  // layer 2 (fused GEMM + epilogue)
  gemm2_k<<<dim3(N / 32, 4), dim3(512), 0, stream>>>(
      x, W1Fh, W1Fl, a1, WhB2, E2, G2, F2, H2);
  attn_k<<<dim3(N / 256, JS2, 4), dim3(512), 0, stream>>>(
      WhB2, E2, G2, F2, H2, pm, (float*)nullptr, 64, (long)N * 64,
      JS2, pAcc2, pSum2);
  combine_k<<<dim3(B * N * 16 / 256), dim3(256), 0, stream>>>(pAcc2, pSum2, img, out, JS2);

  // layer 3 (3b folded in via ticket)
  layer3a_k<<<dim3(B, 8), dim3(256), 0, stream>>>(img, W2, a2, pm, pL3,
                                                  out + (size_t)B * N * 64, ticket);
}

// Round 3
// 162.941 us; speedup vs baseline: 1.0018x; 1.0018x over previous
//
#include <hip/hip_runtime.h>
#include <hip/hip_bf16.h>
#include <cstdint>

// GAT 3-layer pipeline, MI355X. B=4, N=2048, Fin=128, nhid=64, H=8, emb=64, nclass=16.
// fp32 tensors; d_out = [image_feature (4*2048*64) | pre (4*16)] fp32.
// Round 18: r17 structure kept (barrier-free attn, fused gemm2, fused layer3).
// New: (a) XCD-aware block swizzle on gemm1/attn1/attn2 — decode blockIdx.x so each
// XCD's L2 holds a 1MB instance-group of WhB instead of streaming all 8MB (default
// linearization put rowblk%8 on XCDs -> every XCD read every instance). (b)
// s_setprio(1) around attn MFMA cluster (T5: attn waves are phase-diverse, measured
// +4-7%). (c) __launch_bounds__(512,2) on attn_k pins VGPR<=256 (2 waves/SIMD).
// All math bit-identical to r17; absmax must stay exactly 0.0004882812.

#define NN 2048

typedef float f32x4 __attribute__((ext_vector_type(4)));
typedef __bf16 bf16x8 __attribute__((ext_vector_type(8)));
typedef _Float16 f16;
typedef _Float16 f16x8 __attribute__((ext_vector_type(8)));

// ---------------- fused prep: adj->u8 kb-tiled plane, Ws/W1 -> bf16 hi/lo frags ----
// pm layout: [kb(64)][i(2048)][jb(32)] u8 (0xFF if edge) — 4 MB, tiles contiguous.
__global__ __launch_bounds__(256) void prep_k(
    const int* __restrict__ adj, unsigned char* __restrict__ pm,
    const float* __restrict__ Ws, __bf16* __restrict__ WsFh, __bf16* __restrict__ WsFl,
    const float* __restrict__ W1, __bf16* __restrict__ W1Fh, __bf16* __restrict__ W1Fl,
    unsigned int* __restrict__ ticket) {
  const int bx = blockIdx.x, t = threadIdx.x;
  if (bx == 0 && t == 0) *ticket = 0u;  // reset layer3 ticket every graph replay
  if (bx < 2048) {
    const int i = bx;
#pragma unroll
    for (int jt = 0; jt < 8; ++jt) {
      const int j = jt * 256 + t;
      pm[((long)(j >> 5) << 16) + i * 32 + (j & 31)] =
          adj[(long)i * NN + j] > 0 ? 0xFFu : 0u;
    }
  } else if (bx < 2304) {
    const int idx = (bx - 2048) * 256 + t;  // 8 inst x 8192
    const int inst = idx >> 13;
    const int rem = idx & 8191;
    const int k = rem >> 6, n = rem & 63;
    const float v = Ws[(long)inst * 8192 + rem];
    const __bf16 vh = (__bf16)v;
    const int pos = ((k >> 5) * 4 + (n >> 4)) * 512 + (((k >> 3) & 3) * 16 + (n & 15)) * 8 + (k & 7);
    WsFh[(long)inst * 8192 + pos] = vh;
    WsFl[(long)inst * 8192 + pos] = (__bf16)(v - (float)vh);
  } else {
    const int idx = (bx - 2304) * 256 + t;  // 512 x 64
    const int k = idx >> 6, n = idx & 63;
    const float v = W1[idx];
    const __bf16 vh = (__bf16)v;
    const int pos = ((k >> 5) * 4 + (n >> 4)) * 512 + (((k >> 3) & 3) * 16 + (n & 15)) * 8 + (k & 7);
    W1Fh[pos] = vh;
    W1Fl[pos] = (__bf16)(v - (float)vh);
  }
}

// ---------------- MFMA GEMM layer-1 (M rows, N=64). 128 thr, 32 rows/block. --------
// 1-D grid of 2048, XCD-swizzled: xcd = bid&7 hosts batch (xcd&3) x head-group
// ((xcd>>2)*4 + hh) -> per-XCD A working set = one batch's 4MB slices (L2-fit),
// shared by 4 heads.
struct GemmLd {
  float4 a0, a1;
  bf16x8 bh[4], bl[4];
};

__global__ __launch_bounds__(128) void gemm_mfma_k(
    const float* __restrict__ Aall, const __bf16* __restrict__ WFhi,
    const __bf16* __restrict__ WFlo, const float* __restrict__ avecAll,
    f16* __restrict__ WhBAll, float* __restrict__ Eo, float* __restrict__ Go,
    f16* __restrict__ Fo, f16* __restrict__ Ho,
    int K, long aStrideB) {
  const int bid = blockIdx.x;
  const int xcd = bid & 7, r = bid >> 3;
  const int xblk = r & 63, hh = r >> 6;
  const int head = ((xcd >> 2) << 2) + hh;
  const int p = (head << 2) | (xcd & 3);
  const float* A = Aall + (long)(p & 3) * aStrideB;
  const long wfOff = (long)(p >> 2) * K * 64;
  const bf16x8* BhF = (const bf16x8*)(WFhi + wfOff);
  const bf16x8* BlF = (const bf16x8*)(WFlo + wfOff);

  const int t = threadIdx.x, lane = t & 63, wave = t >> 6;
  const int quad = lane >> 4, lm = lane & 15;
  const int i0w = xblk * 32 + wave * 16;
  const float* Arow = A + (long)(i0w + lm) * K;
  const int kBeg = 0, kEnd = K;

  f32x4 acc[4];
#pragma unroll
  for (int nt = 0; nt < 4; ++nt) acc[nt] = (f32x4){0.f, 0.f, 0.f, 0.f};

  auto LOAD = [&](GemmLd& L, int k0) {
    L.a0 = *(const float4*)(Arow + k0 + quad * 8);
    L.a1 = *(const float4*)(Arow + k0 + quad * 8 + 4);
    const int bbase = (k0 >> 5) * 256 + lane;
#pragma unroll
    for (int nt = 0; nt < 4; ++nt) {
      L.bh[nt] = BhF[bbase + nt * 64];
      L.bl[nt] = BlF[bbase + nt * 64];
    }
  };
  auto STEP = [&](const GemmLd& L) {
    const float av8[8] = {L.a0.x, L.a0.y, L.a0.z, L.a0.w, L.a1.x, L.a1.y, L.a1.z, L.a1.w};
    bf16x8 ah, al;
#pragma unroll
    for (int j = 0; j < 8; ++j) {
      const __bf16 h = (__bf16)av8[j];
      ah[j] = h;
      al[j] = (__bf16)(av8[j] - (float)h);
    }
#pragma unroll
    for (int nt = 0; nt < 4; ++nt) {
      acc[nt] = __builtin_amdgcn_mfma_f32_16x16x32_bf16(ah, L.bh[nt], acc[nt], 0, 0, 0);
      acc[nt] = __builtin_amdgcn_mfma_f32_16x16x32_bf16(al, L.bh[nt], acc[nt], 0, 0, 0);
      acc[nt] = __builtin_amdgcn_mfma_f32_16x16x32_bf16(ah, L.bl[nt], acc[nt], 0, 0, 0);
    }
  };

  GemmLd La, Lb;
  LOAD(La, kBeg);
  for (int k0 = kBeg; k0 < kEnd; k0 += 64) {
    LOAD(Lb, k0 + 32);
    STEP(La);
    LOAD(La, (k0 + 64 < kEnd) ? k0 + 64 : kBeg);
    STEP(Lb);
  }

  const float* av = avecAll + (long)(p >> 2) * 128;
  f16* WhB = WhBAll + (long)p * NN * 64;
  float* E = Eo + (long)p * NN;
  float* G = Go + (long)p * NN;
  f16* F = Fo + (long)p * NN;
  f16* Hh = Ho + (long)p * NN;

  float alo[4], ahi[4];
#pragma unroll
  for (int nt = 0; nt < 4; ++nt) {
    alo[nt] = av[nt * 16 + lm];
    ahi[nt] = av[64 + nt * 16 + lm];
  }
#pragma unroll
  for (int reg = 0; reg < 4; ++reg) {
    float es = 0.f, ed = 0.f;
#pragma unroll
    for (int nt = 0; nt < 4; ++nt) {
      es += acc[nt][reg] * alo[nt];
      ed += acc[nt][reg] * ahi[nt];
    }
#pragma unroll
    for (int m = 1; m < 16; m <<= 1) {
      es += __shfl_xor(es, m);
      ed += __shfl_xor(ed, m);
    }
    if (lm == 0) {
      const int r2 = i0w + quad * 4 + reg;
      E[r2] = __expf(es);
      G[r2] = __expf(0.2f * es);
      F[r2] = (f16)__expf(ed);
      Hh[r2] = (f16)__expf(0.2f * ed);
    }
  }

  const int r0 = i0w + quad * 4;
  const long base = ((long)(r0 >> 5) * 4) * 512 + (((r0 >> 3) & 3) * 16 + lm) * 8 + (r0 & 7);
#pragma unroll
  for (int nt = 0; nt < 4; ++nt) {
    union { f16 h[4]; uint2 u; } pk;
#pragma unroll
    for (int q = 0; q < 4; ++q) pk.h[q] = (f16)acc[nt][q];
    *(uint2*)(WhB + base + nt * 512) = pk.u;
  }
}

// ---------------- layer-2 GEMM fused with epilogue (8 waves: 4 K-slices x 2 row-halves)
__global__ __launch_bounds__(512) void gemm2_k(
    const float* __restrict__ Aall, const __bf16* __restrict__ WFhi,
    const __bf16* __restrict__ WFlo, const float* __restrict__ avec,
    f16* __restrict__ WhBAll, float* __restrict__ Eo, float* __restrict__ Go,
    f16* __restrict__ Fo, f16* __restrict__ Ho) {
  const int p = blockIdx.y;
  const float* A = Aall + (long)p * NN * 512;
  const bf16x8* BhF = (const bf16x8*)WFhi;
  const bf16x8* BlF = (const bf16x8*)WFlo;
  const int t = threadIdx.x, lane = t & 63, wave = t >> 6;
  const int ks = wave & 3, rh = wave >> 2;
  const int quad = lane >> 4, lm = lane & 15;
  const int i0 = blockIdx.x * 32;
  const float* Arow = A + (long)(i0 + rh * 16 + lm) * 512;
  const int kBeg = ks * 128, kEnd = kBeg + 128;

  f32x4 acc[4];
#pragma unroll
  for (int nt = 0; nt < 4; ++nt) acc[nt] = (f32x4){0.f, 0.f, 0.f, 0.f};

  auto LOAD = [&](GemmLd& L, int k0) {
    L.a0 = *(const float4*)(Arow + k0 + quad * 8);
    L.a1 = *(const float4*)(Arow + k0 + quad * 8 + 4);
    const int bbase = (k0 >> 5) * 256 + lane;
#pragma unroll
    for (int nt = 0; nt < 4; ++nt) {
      L.bh[nt] = BhF[bbase + nt * 64];
      L.bl[nt] = BlF[bbase + nt * 64];
    }
  };
  auto STEP = [&](const GemmLd& L) {
    const float av8[8] = {L.a0.x, L.a0.y, L.a0.z, L.a0.w, L.a1.x, L.a1.y, L.a1.z, L.a1.w};
    bf16x8 ah, al;
#pragma unroll
    for (int j = 0; j < 8; ++j) {
      const __bf16 h = (__bf16)av8[j];
      ah[j] = h;
      al[j] = (__bf16)(av8[j] - (float)h);
    }
#pragma unroll
    for (int nt = 0; nt < 4; ++nt) {
      acc[nt] = __builtin_amdgcn_mfma_f32_16x16x32_bf16(ah, L.bh[nt], acc[nt], 0, 0, 0);
      acc[nt] = __builtin_amdgcn_mfma_f32_16x16x32_bf16(al, L.bh[nt], acc[nt], 0, 0, 0);
      acc[nt] = __builtin_amdgcn_mfma_f32_16x16x32_bf16(ah, L.bl[nt], acc[nt], 0, 0, 0);
    }
  };

  GemmLd La, Lb;
  LOAD(La, kBeg);
  for (int k0 = kBeg; k0 < kEnd; k0 += 64) {
    LOAD(Lb, k0 + 32);
    STEP(La);
    LOAD(La, (k0 + 64 < kEnd) ? k0 + 64 : kBeg);
    STEP(Lb);
  }

  // cross-wave K reduction: red[wave][nt][lane][reg]
  __shared__ __align__(16) float red[8][4][64][4];
#pragma unroll
  for (int nt = 0; nt < 4; ++nt) *(f32x4*)&red[wave][nt][lane][0] = acc[nt];
  __syncthreads();

  // epilogue: thread (rgrp=wave, n=lane) owns col n of rows rgrp*4..+3
  const int n = lane, rgrp = wave;
  const int rh2 = rgrp >> 2, q2 = rgrp & 3;
  const int ln = q2 * 16 + (n & 15), ntq = n >> 4;
  f32x4 c4 = *(const f32x4*)&red[rh2 * 4 + 0][ntq][ln][0];
#pragma unroll
  for (int ksum = 1; ksum < 4; ++ksum)
    c4 += *(const f32x4*)&red[rh2 * 4 + ksum][ntq][ln][0];

  f32x4 es4 = c4 * avec[n];
  f32x4 ed4 = c4 * avec[64 + n];
#pragma unroll
  for (int m = 1; m < 64; m <<= 1) {
#pragma unroll
    for (int q = 0; q < 4; ++q) {
      es4[q] += __shfl_xor(es4[q], m);
      ed4[q] += __shfl_xor(ed4[q], m);
    }
  }
  const int row0 = i0 + rgrp * 4;
  if (n == 0) {
#pragma unroll
    for (int reg = 0; reg < 4; ++reg) {
      const int row = row0 + reg;
      Eo[(long)p * NN + row] = __expf(es4[reg]);
      Go[(long)p * NN + row] = __expf(0.2f * es4[reg]);
      Fo[(long)p * NN + row] = (f16)__expf(ed4[reg]);
      Ho[(long)p * NN + row] = (f16)__expf(0.2f * ed4[reg]);
    }
  }
  f16* WhB = WhBAll + (long)p * NN * 64;
  union { f16 h[4]; uint2 u; } pk;
#pragma unroll
  for (int reg = 0; reg < 4; ++reg) pk.h[reg] = (f16)c4[reg];
  const long pos = ((long)(row0 >> 5) * 4 + ntq) * 512 +
                   ((((row0 >> 3) & 3) * 16 + (n & 15)) * 8) + (row0 & 7);
  *(uint2*)(WhB + pos) = pk.u;
}

// ---------------- attention: barrier-free, B/F/H direct from L1/L2, 64 rows/wave ----
// 512 thr = 8 waves: rw = wave&3 (64 rows each, block = 256 rows), half = wave>>2
// (kb-half). 1-D grid, XCD-swizzled: layer1 -> XCD x hosts head x (4 batches, 1MB
// WhB hot in L2); layer2 -> XCD x hosts p = x>>1 (512KB hot). s_setprio(1) wraps the
// MFMA cluster (waves are phase-diverse, no main-loop barriers).
struct KbLd {
  f16x8 F8, H8;
  f16x8 b[4];
  uint2 m[4];
};

__global__ __launch_bounds__(512, 2) void attn_k(
    const f16* __restrict__ WhBAll, const float* __restrict__ Eb,
    const float* __restrict__ Gb, const f16* __restrict__ Fb,
    const f16* __restrict__ Hb, const unsigned char* __restrict__ pm,
    float* __restrict__ out1, int rowStride, long strideB,
    int jsCount, float* __restrict__ partAcc, float* __restrict__ partSum) {
  const int bid = blockIdx.x;
  int p, js, rowblk;
  if (jsCount == 1) {            // layer1: 256 blocks, 32 instances
    const int xcd = bid & 7, r = bid >> 3;
    p = xcd * 4 + (r & 3);       // XCD x: head x, batches 0..3
    rowblk = r >> 2;             // 0..7
    js = 0;
  } else {                       // layer2: 128 blocks, 4 instances, js 0..3
    const int xcd = bid & 7;
    const int idx = ((xcd & 1) << 4) + (bid >> 3);
    p = xcd >> 1;
    js = idx >> 3;
    rowblk = idx & 7;
  }
  const f16* WhB = WhBAll + (long)p * NN * 64;
  const float* E = Eb + (long)p * NN;
  const float* G = Gb + (long)p * NN;
  const f16* Fg = Fb + (long)p * NN;
  const f16* Hg = Hb + (long)p * NN;
  const int t = threadIdx.x, lane = t & 63, wave = t >> 6;
  const int rw = wave & 3, half = wave >> 2;
  const int quad = lane >> 4, lm = lane & 15;
  const int i0 = rowblk * 256;
  const int rbase = rw * 64;
  const int span = 64 / jsCount;      // kb per js job
  const int nIter = span / 2;         // kb per half (even, >=8)
  const int kbBeg = js * span + half * nIter, kbEnd = kbBeg + nIter;

  __shared__ __align__(16) float cmb[20480];  // 80 KB half-combine buffer

  f16x8 ev[4], gv[4];
#pragma unroll
  for (int g = 0; g < 4; ++g) {
    const int r = i0 + rbase + g * 16 + lm;
    const f16 e = (f16)E[r], gg = (f16)G[r];
#pragma unroll
    for (int j = 0; j < 8; ++j) { ev[g][j] = e; gv[g][j] = gg; }
  }

  f16x8 ones;
#pragma unroll
  for (int j = 0; j < 8; ++j) ones[j] = (lm == 0) ? (f16)1.0f : (f16)0.0f;

  f32x4 acc[4][4], sum[4];
#pragma unroll
  for (int g = 0; g < 4; ++g) {
    sum[g] = (f32x4){0.f, 0.f, 0.f, 0.f};
#pragma unroll
    for (int nt = 0; nt < 4; ++nt) acc[g][nt] = (f32x4){0.f, 0.f, 0.f, 0.f};
  }

  const unsigned char* mp[4];
#pragma unroll
  for (int g = 0; g < 4; ++g)
    mp[g] = pm + (long)(i0 + rbase + g * 16 + lm) * 32 + quad * 8;

  auto LD = [&](KbLd& L, int kb) {
    L.F8 = *(const f16x8*)(Fg + kb * 32 + quad * 8);
    L.H8 = *(const f16x8*)(Hg + kb * 32 + quad * 8);
#pragma unroll
    for (int nt = 0; nt < 4; ++nt)
      L.b[nt] = *(const f16x8*)(WhB + (long)kb * 2048 + (nt * 64 + lane) * 8);
#pragma unroll
    for (int g = 0; g < 4; ++g)
      L.m[g] = *(const uint2*)(mp[g] + ((long)kb << 16));
  };
  auto CP = [&](const KbLd& L) {
    union { f16x8 v; uint4 u4; } A[4];
#pragma unroll
    for (int g = 0; g < 4; ++g) {
      A[g].v = __builtin_elementwise_max(ev[g] * L.F8, gv[g] * L.H8);
      A[g].u4.x &= __builtin_amdgcn_perm(0u, L.m[g].x, 0x01010000u);
      A[g].u4.y &= __builtin_amdgcn_perm(0u, L.m[g].x, 0x03030202u);
      A[g].u4.z &= __builtin_amdgcn_perm(0u, L.m[g].y, 0x01010000u);
      A[g].u4.w &= __builtin_amdgcn_perm(0u, L.m[g].y, 0x03030202u);
    }
    __builtin_amdgcn_s_setprio(1);
#pragma unroll
    for (int nt = 0; nt < 4; ++nt) {
#pragma unroll
      for (int g = 0; g < 4; ++g)
        acc[g][nt] = __builtin_amdgcn_mfma_f32_16x16x32_f16(A[g].v, L.b[nt], acc[g][nt], 0, 0, 0);
    }
#pragma unroll
    for (int g = 0; g < 4; ++g)
      sum[g] = __builtin_amdgcn_mfma_f32_16x16x32_f16(A[g].v, ones, sum[g], 0, 0, 0);
    __builtin_amdgcn_s_setprio(0);
  };

  KbLd La, Lb2;
  LD(La, kbBeg);
  for (int kb = kbBeg; kb < kbEnd; kb += 2) {
    LD(Lb2, kb + 1);
    CP(La);
    if (kb + 2 < kbEnd) LD(La, kb + 2);
    CP(Lb2);
  }

  // ---- combine the two kb-halves via LDS (chunk-major, lane-contiguous 16B) ----
  if (half == 1) {
#pragma unroll
    for (int g = 0; g < 4; ++g) {
#pragma unroll
      for (int nt = 0; nt < 4; ++nt)
        *(f32x4*)&cmb[((rw * 20 + g * 4 + nt) * 64 + lane) * 4] = acc[g][nt];
      *(f32x4*)&cmb[((rw * 20 + 16 + g) * 64 + lane) * 4] = sum[g];
    }
  }
  __syncthreads();
  if (half == 1) return;
#pragma unroll
  for (int g = 0; g < 4; ++g) {
#pragma unroll
    for (int nt = 0; nt < 4; ++nt)
      acc[g][nt] += *(const f32x4*)&cmb[((rw * 20 + g * 4 + nt) * 64 + lane) * 4];
    sum[g] += *(const f32x4*)&cmb[((rw * 20 + 16 + g) * 64 + lane) * 4];
  }

  if (jsCount == 1) {
#pragma unroll
    for (int g = 0; g < 4; ++g) {
#pragma unroll
      for (int reg = 0; reg < 4; ++reg) {
        const int row = i0 + rbase + g * 16 + quad * 4 + reg;
        const float ls = __shfl(sum[g][reg], quad * 16);
        const float il = ls > 0.f ? 1.f / ls : 0.f;
#pragma unroll
        for (int nt = 0; nt < 4; ++nt) {
          float v = acc[g][nt][reg] * il;
          v = v > 0.f ? v : expm1f(v);  // elu
          const long o = (long)(p & 3) * strideB + (long)row * rowStride + (p >> 2) * 64 + nt * 16 + lm;
          out1[o] = v;
        }
      }
    }
  } else {
    float* pAcc = partAcc + ((long)p * jsCount + js) * NN * 64;
    float* pSum = partSum + ((long)p * jsCount + js) * NN;
#pragma unroll
    for (int g = 0; g < 4; ++g) {
#pragma unroll
      for (int reg = 0; reg < 4; ++reg) {
        const int row = i0 + rbase + g * 16 + quad * 4 + reg;
#pragma unroll
        for (int nt = 0; nt < 4; ++nt) pAcc[(long)row * 64 + nt * 16 + lm] = acc[g][nt][reg];
        if (lm == 0) pSum[row] = sum[g][reg];
      }
    }
  }
}

// ---------------- combine j-split partials: normalize + elu + dual write (512 blocks) ----
__global__ __launch_bounds__(256) void combine_k(const float* __restrict__ partAcc,
                                                 const float* __restrict__ partSum,
                                                 float* __restrict__ img,
                                                 float* __restrict__ out, int JS) {
  const long idx = (long)blockIdx.x * 256 + threadIdx.x;
  const int cg = idx & 15;
  const int row = (int)((idx >> 4) & (NN - 1));
  const int inst = (int)(idx >> 15);
  f32x4 v = (f32x4){0.f, 0.f, 0.f, 0.f};
  float s = 0.f;
  for (int js = 0; js < JS; ++js) {
    const long b = ((long)inst * JS + js) * NN;
    v += *(const f32x4*)(partAcc + (b + row) * 64 + cg * 4);
    s += partSum[b + row];
  }
  const float il = s > 0.f ? 1.f / s : 0.f;
  f32x4 r;
#pragma unroll
  for (int q = 0; q < 4; ++q) {
    float x = v[q] * il;
    r[q] = x > 0.f ? x : expm1f(x);
  }
  const long o = ((long)inst * NN + row) * 64 + cg * 4;
  *(f32x4*)(img + o) = r;
  *(f32x4*)(out + o) = r;
}

// ---------------- layer-3: on-the-fly Wh3, j-split partials; last block reduces ----
__global__ __launch_bounds__(256) void layer3a_k(
    const float* __restrict__ img, const float* __restrict__ W2,
    const float* __restrict__ a2, const unsigned char* __restrict__ pm,
    float* __restrict__ pOut /* [B][8][17] */, float* __restrict__ outPre,
    unsigned int* __restrict__ ticket) {
  const int bb = blockIdx.x, chunk = blockIdx.y, t = threadIdx.x;
  const float* A = img + (long)bb * NN * 64;
  __shared__ float w2alo[64], w2ahi[64];
  __shared__ float W2s[64][17];
  __shared__ float redc[4][17];
  __shared__ int lastS;
  if (t < 64) {
    float sl = 0.f, sh = 0.f;
#pragma unroll
    for (int c = 0; c < 16; ++c) {
      const float wv = W2[t * 16 + c];
      W2s[t][c] = wv;
      sl += wv * a2[c];
      sh += wv * a2[16 + c];
    }
    w2alo[t] = sl;
    w2ahi[t] = sh;
  }
  __syncthreads();

  float es = 0.f;
#pragma unroll 16
  for (int k = 0; k < 64; ++k) es += A[k] * w2alo[k];

  const int j = chunk * 256 + t;
  float arow[64];
#pragma unroll
  for (int q = 0; q < 16; ++q) *(f32x4*)(arow + q * 4) = *(const f32x4*)(A + (long)j * 64 + q * 4);
  float ed = 0.f;
#pragma unroll
  for (int k = 0; k < 64; ++k) ed += arow[k] * w2ahi[k];
  float e = es + ed;
  e = fmaxf(e, 0.2f * e);
  const float pv = pm[((long)(j >> 5) << 16) + (j & 31)] ? __expf(e) : 0.f;  // row 0 mask

  float acc[16];
#pragma unroll
  for (int c = 0; c < 16; ++c) {
    float wh = 0.f;
#pragma unroll
    for (int k = 0; k < 64; ++k) wh += arow[k] * W2s[k][c];
    acc[c] = pv * wh;
  }
  float lsum = pv;

#pragma unroll
  for (int off = 32; off > 0; off >>= 1) {
    lsum += __shfl_down(lsum, off);
#pragma unroll
    for (int c = 0; c < 16; ++c) acc[c] += __shfl_down(acc[c], off);
  }
  if ((t & 63) == 0) {
    const int wv = t >> 6;
#pragma unroll
    for (int c = 0; c < 16; ++c) redc[wv][c] = acc[c];
    redc[wv][16] = lsum;
  }
  __syncthreads();
  if (t < 17) {
    __hip_atomic_store(&pOut[((long)bb * 8 + chunk) * 17 + t],
                       redc[0][t] + redc[1][t] + redc[2][t] + redc[3][t],
                       __ATOMIC_RELAXED, __HIP_MEMORY_SCOPE_AGENT);
  }
  __syncthreads();
  if (t == 0)
    lastS = (__hip_atomic_fetch_add(ticket, 1u, __ATOMIC_ACQ_REL,
                                    __HIP_MEMORY_SCOPE_AGENT) == 31u);
  __syncthreads();
  if (lastS && t < 64) {
    const int b2 = t >> 4, c2 = t & 15;
    float a = 0.f, l = 0.f;
#pragma unroll
    for (int ch = 0; ch < 8; ++ch) {
      a += __hip_atomic_load(&pOut[((long)b2 * 8 + ch) * 17 + c2],
                             __ATOMIC_RELAXED, __HIP_MEMORY_SCOPE_AGENT);
      l += __hip_atomic_load(&pOut[((long)b2 * 8 + ch) * 17 + 16],
                             __ATOMIC_RELAXED, __HIP_MEMORY_SCOPE_AGENT);
    }
    float v = a / l;
    v = v > 0.f ? v : expm1f(v);
    outPre[b2 * 16 + c2] = v;
  }
}

// ---------------- host ----------------
extern "C" void kernel_launch(void* const* d_in, const int* in_sizes, int n_in,
                              void* d_out, int out_size, void* d_ws, size_t ws_size,
                              hipStream_t stream) {
  (void)in_sizes; (void)n_in; (void)out_size; (void)ws_size;
  constexpr int B = 4, N = NN, JS2 = 4;

  const float* slices = (const float*)d_in[0];
  const int* adj = (const int*)d_in[1];
  const float* Ws = (const float*)d_in[2];
  const float* As = (const float*)d_in[3];
  const float* W1 = (const float*)d_in[4];
  const float* a1 = (const float*)d_in[5];
  const float* W2 = (const float*)d_in[6];
  const float* a2 = (const float*)d_in[7];
  float* out = (float*)d_out;

  char* w = (char*)d_ws;
  size_t off = 0;
  auto alloc = [&](size_t bytes) {
    void* ptr = w + off;
    off += (bytes + 255) & ~(size_t)255;
    return ptr;
  };
  unsigned char* pm = (unsigned char*)alloc((size_t)64 * 65536);  // 4 MB kb-tiled mask
  __bf16* WsFh = (__bf16*)alloc((size_t)8 * 128 * 64 * 2);
  __bf16* WsFl = (__bf16*)alloc((size_t)8 * 128 * 64 * 2);
  __bf16* W1Fh = (__bf16*)alloc((size_t)512 * 64 * 2);
  __bf16* W1Fl = (__bf16*)alloc((size_t)512 * 64 * 2);
  f16* WhB1 = (f16*)alloc((size_t)32 * N * 64 * 2);  // 8 MB
  float* E1 = (float*)alloc((size_t)32 * N * 4);
  float* G1 = (float*)alloc((size_t)32 * N * 4);
  f16* F1 = (f16*)alloc((size_t)32 * N * 2);
  f16* H1 = (f16*)alloc((size_t)32 * N * 2);
  float* x = (float*)alloc((size_t)B * N * 512 * 4);  // 16 MB
  f16* WhB2 = (f16*)alloc((size_t)B * N * 64 * 2);
  float* E2 = (float*)alloc((size_t)B * N * 4);
  float* G2 = (float*)alloc((size_t)B * N * 4);
  f16* F2 = (f16*)alloc((size_t)B * N * 2);
  f16* H2 = (f16*)alloc((size_t)B * N * 2);
  float* img = (float*)alloc((size_t)B * N * 64 * 4);  // 2 MB
  float* pAcc2 = (float*)alloc((size_t)B * JS2 * N * 64 * 4);  // 8 MB
  float* pSum2 = (float*)alloc((size_t)B * JS2 * N * 4);
  float* pL3 = (float*)alloc((size_t)B * 8 * 17 * 4);
  unsigned int* ticket = (unsigned int*)alloc(256);

  prep_k<<<dim3(2432), dim3(256), 0, stream>>>(adj, pm, Ws, WsFh, WsFl, W1, W1Fh, W1Fl, ticket);

  // layer 1 (XCD-swizzled 1-D grids)
  gemm_mfma_k<<<dim3(2048), dim3(128), 0, stream>>>(
      slices, WsFh, WsFl, As, WhB1, E1, G1, F1, H1, 128, (long)N * 128);
  attn_k<<<dim3(256), dim3(512), 0, stream>>>(
      WhB1, E1, G1, F1, H1, pm, x, 512, (long)N * 512,
      1, (float*)nullptr, (float*)nullptr);

  // layer 2 (fused GEMM + epilogue; attn XCD-swizzled)
  gemm2_k<<<dim3(N / 32, 4), dim3(512), 0, stream>>>(
      x, W1Fh, W1Fl, a1, WhB2, E2, G2, F2, H2);
  attn_k<<<dim3(128), dim3(512), 0, stream>>>(
      WhB2, E2, G2, F2, H2, pm, (float*)nullptr, 64, (long)N * 64,
      JS2, pAcc2, pSum2);
  combine_k<<<dim3(B * N * 16 / 256), dim3(256), 0, stream>>>(pAcc2, pSum2, img, out, JS2);

  // layer 3 (3b folded in via ticket)
  layer3a_k<<<dim3(B, 8), dim3(256), 0, stream>>>(img, W2, a2, pm, pL3,
                                                  out + (size_t)B * N * 64, ticket);
}